// Round 1
// baseline (138.694 us; speedup 1.0000x reference)
//
#include <hip/hip_runtime.h>

// LCN spiking net, round 6: 2 dispatches.
//  - Key fact: the gather h[:, knn] couples FEATURES only; rows (batch at
//    t=T-1) are fully independent, and per-row activations after layer 0
//    total 55.8 KB -> layers 1-4 + FC fit in one block's LDS per row.
//  - K1: layer 0 (14400->7200) over 256 blocks (8 chunks x 32 rows), x-row
//    staged in LDS; writes h1 ROW-major so K2 can stage a row coalesced.
//  - K2: one block per row (32 blocks x 1024 threads). All intermediates in
//    LDS, only block-local __syncthreads() between layers. FC epilogue
//    reduces in-wave (shfl) + LDS atomics and writes out[2r],out[2r+1]
//    directly -> no memset dispatch, no global atomics.
//  - Eliminates 4 inter-layer dispatch boundaries + memset node (6 -> 2).

#define ROWS 32
#define TSTEPS 20
#define D0 14400
#define D1 7200
#define D2 3600
#define D3 1800
#define D4 900
#define D5 450
#define KNB 25

// K1: layer 0. Grid (8, ROWS), block 256. Stage x row in LDS, gather,
// write h1 row-major (coalesced: consecutive threads -> consecutive j).
__global__ __launch_bounds__(256)
void l0_stage(const float* __restrict__ x, float* __restrict__ h1,
              const float* __restrict__ w, const float* __restrict__ bvec,
              const int* __restrict__ knn)
{
    __shared__ float s[D0];   // 57.6 KB
    const int r = blockIdx.y;
    const float* xrow = x + ((size_t)r * TSTEPS + (TSTEPS - 1)) * (size_t)D0;

    const float4* src = reinterpret_cast<const float4*>(xrow);
    float4* dst = reinterpret_cast<float4*>(s);
#pragma unroll 1
    for (int i = threadIdx.x; i < D0 / 4; i += 256)
        dst[i] = src[i];
    __syncthreads();

    const int j0 = blockIdx.x * 900;
#pragma unroll 1
    for (int j = j0 + threadIdx.x; j < j0 + 900; j += 256) {
        const int*   kn = knn + j * KNB;
        const float* ww = w   + j * KNB;
        float acc = bvec[j];
#pragma unroll
        for (int k = 0; k < KNB; ++k)
            acc += s[kn[k]] * ww[k];
        h1[(size_t)r * D1 + j] = acc;   // row-major write
    }
}

// K2: layers 1-4 + FC, one block per row. 55.8 KB LDS of activations.
__global__ __launch_bounds__(1024)
void tail_fused(const float* __restrict__ h1,
                const float* __restrict__ w1, const float* __restrict__ b1, const int* __restrict__ n1,
                const float* __restrict__ w2, const float* __restrict__ b2, const int* __restrict__ n2,
                const float* __restrict__ w3, const float* __restrict__ b3, const int* __restrict__ n3,
                const float* __restrict__ w4, const float* __restrict__ b4, const int* __restrict__ n4,
                const float* __restrict__ Wfc, const float* __restrict__ bfc,
                float* __restrict__ out)
{
    __shared__ float sa[D1];  // 28.8 KB  layer-1 input
    __shared__ float sb[D2];  // 14.4 KB
    __shared__ float sc[D3];  //  7.2 KB
    __shared__ float sd[D4];  //  3.6 KB
    __shared__ float se[D5];  //  1.8 KB
    __shared__ float red[2];

    const int r   = blockIdx.x;
    const int tid = threadIdx.x;

    // stage this row of h1 (28.8 KB, coalesced float4)
    {
        const float4* src = reinterpret_cast<const float4*>(h1 + (size_t)r * D1);
        float4* dst = reinterpret_cast<float4*>(sa);
#pragma unroll 1
        for (int i = tid; i < D1 / 4; i += 1024)
            dst[i] = src[i];
    }
    __syncthreads();

    // layer 1: 7200 -> 3600
#pragma unroll 1
    for (int j = tid; j < D2; j += 1024) {
        const int*   kn = n1 + j * KNB;
        const float* ww = w1 + j * KNB;
        float acc = b1[j];
#pragma unroll
        for (int k = 0; k < KNB; ++k)
            acc += sa[kn[k]] * ww[k];
        sb[j] = acc;
    }
    __syncthreads();

    // layer 2: 3600 -> 1800
#pragma unroll 1
    for (int j = tid; j < D3; j += 1024) {
        const int*   kn = n2 + j * KNB;
        const float* ww = w2 + j * KNB;
        float acc = b2[j];
#pragma unroll
        for (int k = 0; k < KNB; ++k)
            acc += sb[kn[k]] * ww[k];
        sc[j] = acc;
    }
    __syncthreads();

    // layer 3: 1800 -> 900
#pragma unroll 1
    for (int j = tid; j < D4; j += 1024) {
        const int*   kn = n3 + j * KNB;
        const float* ww = w3 + j * KNB;
        float acc = b3[j];
#pragma unroll
        for (int k = 0; k < KNB; ++k)
            acc += sc[kn[k]] * ww[k];
        sd[j] = acc;
    }
    __syncthreads();

    // layer 4: 900 -> 450
#pragma unroll 1
    for (int j = tid; j < D5; j += 1024) {
        const int*   kn = n4 + j * KNB;
        const float* ww = w4 + j * KNB;
        float acc = b4[j];
#pragma unroll
        for (int k = 0; k < KNB; ++k)
            acc += sd[kn[k]] * ww[k];
        se[j] = acc;
    }
    __syncthreads();

    if (tid == 0) { red[0] = bfc[0]; red[1] = bfc[1]; }

    // FC: 450 -> 2 (threads >= D5 contribute 0)
    float c0 = 0.0f, c1 = 0.0f;
#pragma unroll 1
    for (int j = tid; j < D5; j += 1024) {
        const float v = se[j];
        c0 += v * Wfc[2 * j + 0];
        c1 += v * Wfc[2 * j + 1];
    }
#pragma unroll
    for (int off = 32; off > 0; off >>= 1) {
        c0 += __shfl_down(c0, off);
        c1 += __shfl_down(c1, off);
    }
    __syncthreads();   // red[] initialized before atomics
    if ((tid & 63) == 0) {
        atomicAdd(&red[0], c0);
        atomicAdd(&red[1], c1);
    }
    __syncthreads();
    if (tid < 2)
        out[2 * r + tid] = red[tid];
}

extern "C" void kernel_launch(void* const* d_in, const int* in_sizes, int n_in,
                              void* d_out, int out_size, void* d_ws, size_t ws_size,
                              hipStream_t stream)
{
    const float* x    = (const float*)d_in[0];
    const float* w0   = (const float*)d_in[1];
    const float* b0   = (const float*)d_in[2];
    const int*   knn0 = (const int*)  d_in[3];
    const float* w1   = (const float*)d_in[4];
    const float* b1   = (const float*)d_in[5];
    const int*   knn1 = (const int*)  d_in[6];
    const float* w2   = (const float*)d_in[7];
    const float* b2   = (const float*)d_in[8];
    const int*   knn2 = (const int*)  d_in[9];
    const float* w3   = (const float*)d_in[10];
    const float* b3   = (const float*)d_in[11];
    const int*   knn3 = (const int*)  d_in[12];
    const float* w4   = (const float*)d_in[13];
    const float* b4   = (const float*)d_in[14];
    const int*   knn4 = (const int*)  d_in[15];
    const float* Wfc  = (const float*)d_in[16];
    const float* bfc  = (const float*)d_in[17];
    float* out = (float*)d_out;

    // h1[32][7200] row-major in workspace (921.6 KB)
    float* h1 = (float*)d_ws;

    // layer 0: x[:,T-1,:] -> h1 (row-major)
    l0_stage<<<dim3(D1 / 900, ROWS), dim3(256), 0, stream>>>(x, h1, w0, b0, knn0);

    // layers 1-4 + FC: one block per row, out written directly (no memset)
    tail_fused<<<dim3(ROWS), dim3(1024), 0, stream>>>(
        h1,
        w1, b1, knn1,
        w2, b2, knn2,
        w3, b3, knn3,
        w4, b4, knn4,
        Wfc, bfc, out);
}

// Round 2
// 134.026 us; speedup vs baseline: 1.0348x; 1.0348x over previous
//
#include <hip/hip_runtime.h>

// LCN spiking net, round 7: 3-dispatch hybrid.
//  - Round-6 lesson: fusing layer 1 into a 32-block tail REGRESSED (-8us):
//    3600x25 random LDS gathers + 720KB weight pull on 32 CUs is slower than
//    a full-chip transposed dispatch + one boundary. Fusion only pays for
//    the small layers.
//  - K1: layer 0 (14400->7200), 256 blocks, x-row staged in LDS, writes
//    TRANSPOSED h1t[j][32] for K2's coalesced gather.
//  - K2: layer 1 (7200->3600) full-chip transposed gather (round-5 kernel):
//    wave = 2 outputs x 32 rows, each gather = 2 contiguous 128B lines,
//    weights near-wave-uniform.
//  - K3: layers 2-4 + FC fused, one block per row (32 x 512). h2t row staged
//    in LDS (L2-hot), then 1800/900/450-output LDS-gather layers + FC with
//    shfl reduce; writes out[2r],out[2r+1] directly (no memset, no atomics).

#define ROWS 32
#define TSTEPS 20
#define D0 14400
#define D1 7200
#define D2 3600
#define D3 1800
#define D4 900
#define D5 450
#define KNB 25

// K1: layer 0. Grid (8, ROWS), block 256. Stage x row in LDS, gather,
// write h1t transposed.
__global__ __launch_bounds__(256)
void l0_stage(const float* __restrict__ x, float* __restrict__ h1t,
              const float* __restrict__ w, const float* __restrict__ bvec,
              const int* __restrict__ knn)
{
    __shared__ float s[D0];   // 57.6 KB
    const int r = blockIdx.y;
    const float* xrow = x + ((size_t)r * TSTEPS + (TSTEPS - 1)) * (size_t)D0;

    const float4* src = reinterpret_cast<const float4*>(xrow);
    float4* dst = reinterpret_cast<float4*>(s);
#pragma unroll 1
    for (int i = threadIdx.x; i < D0 / 4; i += 256)
        dst[i] = src[i];
    __syncthreads();

    const int j0 = blockIdx.x * 900;
#pragma unroll 1
    for (int j = j0 + threadIdx.x; j < j0 + 900; j += 256) {
        const int*   kn = knn + j * KNB;
        const float* ww = w   + j * KNB;
        float acc = bvec[j];
#pragma unroll
        for (int k = 0; k < KNB; ++k)
            acc += s[kn[k]] * ww[k];
        h1t[(j << 5) + r] = acc;   // transposed write
    }
}

// K2: layer 1, transposed gather: pout[j][r] = b[j] + sum_k pin[knn[j][k]][r]*w[j][k]
// Wave = 2 outputs x 32 rows; each gather touches 2 contiguous 128B lines.
__global__ __launch_bounds__(256)
void layer_t_k(const float* __restrict__ pin, float* __restrict__ pout,
               const float* __restrict__ w, const float* __restrict__ bvec,
               const int* __restrict__ knn, int npairs)
{
    const int lane = threadIdx.x & 63;
    const int r  = lane & 31;
    const int jj = lane >> 5;
    const int nw = gridDim.x << 2;
#pragma unroll 1
    for (int jp = (blockIdx.x << 2) + (threadIdx.x >> 6); jp < npairs; jp += nw) {
        const int j = (jp << 1) + jj;
        const int*   kn = knn + j * KNB;
        const float* ww = w   + j * KNB;
        float acc = bvec[j];
#pragma unroll
        for (int k = 0; k < KNB; ++k)
            acc += pin[(kn[k] << 5) + r] * ww[k];
        pout[(j << 5) + r] = acc;
    }
}

// K3: layers 2-4 + FC, one block per row. h2t row staged from transposed
// layout (L2-hot), then all-LDS gather chain, FC shfl-reduce, direct write.
__global__ __launch_bounds__(512)
void tail_fused(const float* __restrict__ h2t,
                const float* __restrict__ w2, const float* __restrict__ b2, const int* __restrict__ n2,
                const float* __restrict__ w3, const float* __restrict__ b3, const int* __restrict__ n3,
                const float* __restrict__ w4, const float* __restrict__ b4, const int* __restrict__ n4,
                const float* __restrict__ Wfc, const float* __restrict__ bfc,
                float* __restrict__ out)
{
    __shared__ float s2[D2];  // 14.4 KB
    __shared__ float s3[D3];  //  7.2 KB
    __shared__ float s4[D4];  //  3.6 KB
    __shared__ float s5[D5];  //  1.8 KB
    __shared__ float red[2];

    const int r   = blockIdx.x;
    const int tid = threadIdx.x;

    // stage this row from transposed h2t (4B/lane, L2-resident)
#pragma unroll 1
    for (int j = tid; j < D2; j += 512)
        s2[j] = h2t[(j << 5) + r];
    __syncthreads();

    // layer 2: 3600 -> 1800
#pragma unroll 1
    for (int j = tid; j < D3; j += 512) {
        const int*   kn = n2 + j * KNB;
        const float* ww = w2 + j * KNB;
        float acc = b2[j];
#pragma unroll
        for (int k = 0; k < KNB; ++k)
            acc += s2[kn[k]] * ww[k];
        s3[j] = acc;
    }
    __syncthreads();

    // layer 3: 1800 -> 900
#pragma unroll 1
    for (int j = tid; j < D4; j += 512) {
        const int*   kn = n3 + j * KNB;
        const float* ww = w3 + j * KNB;
        float acc = b3[j];
#pragma unroll
        for (int k = 0; k < KNB; ++k)
            acc += s3[kn[k]] * ww[k];
        s4[j] = acc;
    }
    __syncthreads();

    // layer 4: 900 -> 450
#pragma unroll 1
    for (int j = tid; j < D5; j += 512) {
        const int*   kn = n4 + j * KNB;
        const float* ww = w4 + j * KNB;
        float acc = b4[j];
#pragma unroll
        for (int k = 0; k < KNB; ++k)
            acc += s4[kn[k]] * ww[k];
        s5[j] = acc;
    }

    if (tid == 0) { red[0] = bfc[0]; red[1] = bfc[1]; }
    __syncthreads();

    // FC: 450 -> 2
    float c0 = 0.0f, c1 = 0.0f;
    if (tid < D5) {
        const float v = s5[tid];
        c0 = v * Wfc[2 * tid + 0];
        c1 = v * Wfc[2 * tid + 1];
    }
#pragma unroll
    for (int off = 32; off > 0; off >>= 1) {
        c0 += __shfl_down(c0, off);
        c1 += __shfl_down(c1, off);
    }
    if ((tid & 63) == 0) {
        atomicAdd(&red[0], c0);
        atomicAdd(&red[1], c1);
    }
    __syncthreads();
    if (tid < 2)
        out[2 * r + tid] = red[tid];
}

extern "C" void kernel_launch(void* const* d_in, const int* in_sizes, int n_in,
                              void* d_out, int out_size, void* d_ws, size_t ws_size,
                              hipStream_t stream)
{
    const float* x    = (const float*)d_in[0];
    const float* w0   = (const float*)d_in[1];
    const float* b0   = (const float*)d_in[2];
    const int*   knn0 = (const int*)  d_in[3];
    const float* w1   = (const float*)d_in[4];
    const float* b1   = (const float*)d_in[5];
    const int*   knn1 = (const int*)  d_in[6];
    const float* w2   = (const float*)d_in[7];
    const float* b2   = (const float*)d_in[8];
    const int*   knn2 = (const int*)  d_in[9];
    const float* w3   = (const float*)d_in[10];
    const float* b3   = (const float*)d_in[11];
    const int*   knn3 = (const int*)  d_in[12];
    const float* w4   = (const float*)d_in[13];
    const float* b4   = (const float*)d_in[14];
    const int*   knn4 = (const int*)  d_in[15];
    const float* Wfc  = (const float*)d_in[16];
    const float* bfc  = (const float*)d_in[17];
    float* out = (float*)d_out;

    // transposed intermediates in ws: h1t[D1][32] | h2t[D2][32]
    float* h1t = (float*)d_ws;
    float* h2t = h1t + (size_t)D1 * ROWS;

    // layer 0: x[:,T-1,:] -> h1t (transposed)
    l0_stage<<<dim3(D1 / 900, ROWS), dim3(256), 0, stream>>>(x, h1t, w0, b0, knn0);

    // layer 1: h1t -> h2t (full chip, 1800 output-pairs)
    layer_t_k<<<dim3(450), dim3(256), 0, stream>>>(h1t, h2t, w1, b1, knn1, D2 / 2);

    // layers 2-4 + FC: one block per row, direct write (no memset)
    tail_fused<<<dim3(ROWS), dim3(512), 0, stream>>>(
        h2t,
        w2, b2, knn2,
        w3, b3, knn3,
        w4, b4, knn4,
        Wfc, bfc, out);
}

// Round 3
// 129.585 us; speedup vs baseline: 1.0703x; 1.0343x over previous
//
#include <hip/hip_runtime.h>

// LCN spiking net, round 8: 4-dispatch with layout handoff.
//  - Evidence r5/r6/r7: fills (2x 256MiB poison ~86us) are the floor; fusing
//    BIG layers onto 32 CUs loses per-CU bandwidth (r7 tail: 460KB/CU
//    uncoalesced stage + 630KB/CU weights) faster than boundaries save.
//  - Fix: fuse only the cheap tail (l3+l4+FC: 270KB weights/CU), and have
//    l2 write h3 ROW-major (scatter spread over 225 full-chip blocks is
//    free) so the tail stages coalesced float4 instead of r7's 128B-line
//    amplified transposed read.
//  - Nodes: l0 (x->h1t transposed), l1 (h1t->h2t transposed), l2
//    (h2t->h3 row-major), tail (l3+l4+FC per row, direct out write).
//    No memset node, no global atomics.

#define ROWS 32
#define TSTEPS 20
#define D0 14400
#define D1 7200
#define D2 3600
#define D3 1800
#define D4 900
#define D5 450
#define KNB 25

// K1: layer 0. Grid (8, ROWS), block 256. Stage x row in LDS, gather,
// write h1t transposed.
__global__ __launch_bounds__(256)
void l0_stage(const float* __restrict__ x, float* __restrict__ h1t,
              const float* __restrict__ w, const float* __restrict__ bvec,
              const int* __restrict__ knn)
{
    __shared__ float s[D0];   // 57.6 KB
    const int r = blockIdx.y;
    const float* xrow = x + ((size_t)r * TSTEPS + (TSTEPS - 1)) * (size_t)D0;

    const float4* src = reinterpret_cast<const float4*>(xrow);
    float4* dst = reinterpret_cast<float4*>(s);
#pragma unroll 1
    for (int i = threadIdx.x; i < D0 / 4; i += 256)
        dst[i] = src[i];
    __syncthreads();

    const int j0 = blockIdx.x * 900;
#pragma unroll 1
    for (int j = j0 + threadIdx.x; j < j0 + 900; j += 256) {
        const int*   kn = knn + j * KNB;
        const float* ww = w   + j * KNB;
        float acc = bvec[j];
#pragma unroll
        for (int k = 0; k < KNB; ++k)
            acc += s[kn[k]] * ww[k];
        h1t[(j << 5) + r] = acc;   // transposed write
    }
}

// K2: transposed gather -> transposed write.
// pout[j][r] = b[j] + sum_k pin[knn[j][k]][r]*w[j][k]
// Wave = 2 outputs x 32 rows; each gather touches 2 contiguous 128B lines.
__global__ __launch_bounds__(256)
void layer_t_k(const float* __restrict__ pin, float* __restrict__ pout,
               const float* __restrict__ w, const float* __restrict__ bvec,
               const int* __restrict__ knn, int npairs)
{
    const int lane = threadIdx.x & 63;
    const int r  = lane & 31;
    const int jj = lane >> 5;
    const int nw = gridDim.x << 2;
#pragma unroll 1
    for (int jp = (blockIdx.x << 2) + (threadIdx.x >> 6); jp < npairs; jp += nw) {
        const int j = (jp << 1) + jj;
        const int*   kn = knn + j * KNB;
        const float* ww = w   + j * KNB;
        float acc = bvec[j];
#pragma unroll
        for (int k = 0; k < KNB; ++k)
            acc += pin[(kn[k] << 5) + r] * ww[k];
        pout[(j << 5) + r] = acc;
    }
}

// K3: transposed gather -> ROW-major write (for the tail's coalesced stage).
// pout[r][j] = b[j] + sum_k pin[knn[j][k]][r]*w[j][k]
__global__ __launch_bounds__(256)
void layer_t_k_rm(const float* __restrict__ pin, float* __restrict__ pout,
                  const float* __restrict__ w, const float* __restrict__ bvec,
                  const int* __restrict__ knn, int npairs, int dout)
{
    const int lane = threadIdx.x & 63;
    const int r  = lane & 31;
    const int jj = lane >> 5;
    const int nw = gridDim.x << 2;
#pragma unroll 1
    for (int jp = (blockIdx.x << 2) + (threadIdx.x >> 6); jp < npairs; jp += nw) {
        const int j = (jp << 1) + jj;
        const int*   kn = knn + j * KNB;
        const float* ww = w   + j * KNB;
        float acc = bvec[j];
#pragma unroll
        for (int k = 0; k < KNB; ++k)
            acc += pin[(kn[k] << 5) + r] * ww[k];
        pout[r * dout + j] = acc;   // row-major scatter (spread full-chip)
    }
}

// K4: layers 3-4 + FC, one block per row (32 x 512).
// Stage h3 row coalesced (7.2 KB), LDS gather chain, shfl-reduce FC,
// direct out write. Per-CU weight traffic: 270 KB (~2 us).
__global__ __launch_bounds__(512)
void tail34fc(const float* __restrict__ h3,
              const float* __restrict__ w3, const float* __restrict__ b3, const int* __restrict__ n3,
              const float* __restrict__ w4, const float* __restrict__ b4, const int* __restrict__ n4,
              const float* __restrict__ Wfc, const float* __restrict__ bfc,
              float* __restrict__ out)
{
    __shared__ float s3[D3];  // 7.2 KB
    __shared__ float s4[D4];  // 3.6 KB
    __shared__ float s5[D5];  // 1.8 KB
    __shared__ float red[2];

    const int r   = blockIdx.x;
    const int tid = threadIdx.x;

    // stage this row of h3 (coalesced float4)
    {
        const float4* src = reinterpret_cast<const float4*>(h3 + (size_t)r * D3);
        float4* dst = reinterpret_cast<float4*>(s3);
#pragma unroll 1
        for (int i = tid; i < D3 / 4; i += 512)
            dst[i] = src[i];
    }
    __syncthreads();

    // layer 3: 1800 -> 900
#pragma unroll 1
    for (int j = tid; j < D4; j += 512) {
        const int*   kn = n3 + j * KNB;
        const float* ww = w3 + j * KNB;
        float acc = b3[j];
#pragma unroll
        for (int k = 0; k < KNB; ++k)
            acc += s3[kn[k]] * ww[k];
        s4[j] = acc;
    }
    __syncthreads();

    // layer 4: 900 -> 450
#pragma unroll 1
    for (int j = tid; j < D5; j += 512) {
        const int*   kn = n4 + j * KNB;
        const float* ww = w4 + j * KNB;
        float acc = b4[j];
#pragma unroll
        for (int k = 0; k < KNB; ++k)
            acc += s4[kn[k]] * ww[k];
        s5[j] = acc;
    }

    if (tid == 0) { red[0] = bfc[0]; red[1] = bfc[1]; }
    __syncthreads();

    // FC: 450 -> 2
    float c0 = 0.0f, c1 = 0.0f;
    if (tid < D5) {
        const float v = s5[tid];
        c0 = v * Wfc[2 * tid + 0];
        c1 = v * Wfc[2 * tid + 1];
    }
#pragma unroll
    for (int off = 32; off > 0; off >>= 1) {
        c0 += __shfl_down(c0, off);
        c1 += __shfl_down(c1, off);
    }
    if ((tid & 63) == 0) {
        atomicAdd(&red[0], c0);
        atomicAdd(&red[1], c1);
    }
    __syncthreads();
    if (tid < 2)
        out[2 * r + tid] = red[tid];
}

extern "C" void kernel_launch(void* const* d_in, const int* in_sizes, int n_in,
                              void* d_out, int out_size, void* d_ws, size_t ws_size,
                              hipStream_t stream)
{
    const float* x    = (const float*)d_in[0];
    const float* w0   = (const float*)d_in[1];
    const float* b0   = (const float*)d_in[2];
    const int*   knn0 = (const int*)  d_in[3];
    const float* w1   = (const float*)d_in[4];
    const float* b1   = (const float*)d_in[5];
    const int*   knn1 = (const int*)  d_in[6];
    const float* w2   = (const float*)d_in[7];
    const float* b2   = (const float*)d_in[8];
    const int*   knn2 = (const int*)  d_in[9];
    const float* w3   = (const float*)d_in[10];
    const float* b3   = (const float*)d_in[11];
    const int*   knn3 = (const int*)  d_in[12];
    const float* w4   = (const float*)d_in[13];
    const float* b4   = (const float*)d_in[14];
    const int*   knn4 = (const int*)  d_in[15];
    const float* Wfc  = (const float*)d_in[16];
    const float* bfc  = (const float*)d_in[17];
    float* out = (float*)d_out;

    // ws: h1t[D1][32] transposed | h2t[D2][32] transposed | h3[32][D3] row-major
    float* h1t = (float*)d_ws;
    float* h2t = h1t + (size_t)D1 * ROWS;
    float* h3  = h2t + (size_t)D2 * ROWS;

    // layer 0: x[:,T-1,:] -> h1t (transposed)
    l0_stage<<<dim3(D1 / 900, ROWS), dim3(256), 0, stream>>>(x, h1t, w0, b0, knn0);

    // layer 1: h1t -> h2t (full chip, 1800 pairs, transposed write)
    layer_t_k<<<dim3(450), dim3(256), 0, stream>>>(h1t, h2t, w1, b1, knn1, D2 / 2);

    // layer 2: h2t -> h3 (full chip, 900 pairs, ROW-major write)
    layer_t_k_rm<<<dim3(225), dim3(256), 0, stream>>>(h2t, h3, w2, b2, knn2, D3 / 2, D3);

    // layers 3-4 + FC: one block per row, direct write (no memset)
    tail34fc<<<dim3(ROWS), dim3(512), 0, stream>>>(
        h3,
        w3, b3, knn3,
        w4, b4, knn4,
        Wfc, bfc, out);
}

// Round 4
// 126.072 us; speedup vs baseline: 1.1001x; 1.0279x over previous
//
#include <hip/hip_runtime.h>

// LCN spiking net, round 9: r8 structure + coalescing fixes.
//  - r5/r7/r8 bounded dispatch-boundary cost at ~1-2us -> node count (4) is
//    exhausted; the ~35us of kernel time vs ~5MB of unique traffic says the
//    bodies are transaction-bound, not BW-bound.
//  - Culprit: per-thread scalar knn/w reads (stride 100B across a wave =
//    ~64 lines PER LOAD, 50 loads per j). Fix: int4/float4 via memcpy
//    (6x16B + 1 scalar per 25-elem row) -> 13 wave-loads per j-set.
//    Applies to l0_stage and tail34fc (layer_t_k weights are already
//    half-wave-uniform broadcasts).
//  - l0 stage loop unroll x2 (more loads in flight); tail widened to 1024
//    threads so l3/l4 are single-iteration and 16 waves hide the weight pull.

#define ROWS 32
#define TSTEPS 20
#define D0 14400
#define D1 7200
#define D2 3600
#define D3 1800
#define D4 900
#define D5 450
#define KNB 25

// gather 25 ints/floats with 16B loads (4B-aligned -> memcpy is safe either way)
#define GATHER25(acc, kp, wp, SRC)                                  \
    {                                                               \
        _Pragma("unroll")                                           \
        for (int k = 0; k < 24; k += 4) {                           \
            int4   ki; __builtin_memcpy(&ki, (kp) + k, 16);         \
            float4 wi; __builtin_memcpy(&wi, (wp) + k, 16);         \
            acc += SRC(ki.x) * wi.x + SRC(ki.y) * wi.y              \
                 + SRC(ki.z) * wi.z + SRC(ki.w) * wi.w;             \
        }                                                           \
        acc += SRC((kp)[24]) * (wp)[24];                            \
    }

// K1: layer 0. Grid (8, ROWS), block 256. Stage x row in LDS, gather,
// write h1t transposed.
__global__ __launch_bounds__(256)
void l0_stage(const float* __restrict__ x, float* __restrict__ h1t,
              const float* __restrict__ w, const float* __restrict__ bvec,
              const int* __restrict__ knn)
{
    __shared__ float s[D0];   // 57.6 KB
    const int r = blockIdx.y;
    const float* xrow = x + ((size_t)r * TSTEPS + (TSTEPS - 1)) * (size_t)D0;

    const float4* src = reinterpret_cast<const float4*>(xrow);
    float4* dst = reinterpret_cast<float4*>(s);
#pragma unroll 2
    for (int i = threadIdx.x; i < D0 / 4; i += 256)
        dst[i] = src[i];
    __syncthreads();

    const int j0 = blockIdx.x * 900;
#pragma unroll 1
    for (int j = j0 + threadIdx.x; j < j0 + 900; j += 256) {
        const int*   kn = knn + j * KNB;
        const float* ww = w   + j * KNB;
        float acc = bvec[j];
#define LDS_SRC(idx) s[idx]
        GATHER25(acc, kn, ww, LDS_SRC)
#undef LDS_SRC
        h1t[(j << 5) + r] = acc;   // transposed write
    }
}

// K2: transposed gather -> transposed write.
// pout[j][r] = b[j] + sum_k pin[knn[j][k]][r]*w[j][k]
// Wave = 2 outputs x 32 rows; kn/w loads are half-wave-uniform (broadcast).
__global__ __launch_bounds__(256)
void layer_t_k(const float* __restrict__ pin, float* __restrict__ pout,
               const float* __restrict__ w, const float* __restrict__ bvec,
               const int* __restrict__ knn, int npairs)
{
    const int lane = threadIdx.x & 63;
    const int r  = lane & 31;
    const int jj = lane >> 5;
    const int nw = gridDim.x << 2;
#pragma unroll 1
    for (int jp = (blockIdx.x << 2) + (threadIdx.x >> 6); jp < npairs; jp += nw) {
        const int j = (jp << 1) + jj;
        const int*   kn = knn + j * KNB;
        const float* ww = w   + j * KNB;
        float acc = bvec[j];
#pragma unroll
        for (int k = 0; k < KNB; ++k)
            acc += pin[(kn[k] << 5) + r] * ww[k];
        pout[(j << 5) + r] = acc;
    }
}

// K3: transposed gather -> ROW-major write (for the tail's coalesced stage).
__global__ __launch_bounds__(256)
void layer_t_k_rm(const float* __restrict__ pin, float* __restrict__ pout,
                  const float* __restrict__ w, const float* __restrict__ bvec,
                  const int* __restrict__ knn, int npairs, int dout)
{
    const int lane = threadIdx.x & 63;
    const int r  = lane & 31;
    const int jj = lane >> 5;
    const int nw = gridDim.x << 2;
#pragma unroll 1
    for (int jp = (blockIdx.x << 2) + (threadIdx.x >> 6); jp < npairs; jp += nw) {
        const int j = (jp << 1) + jj;
        const int*   kn = knn + j * KNB;
        const float* ww = w   + j * KNB;
        float acc = bvec[j];
#pragma unroll
        for (int k = 0; k < KNB; ++k)
            acc += pin[(kn[k] << 5) + r] * ww[k];
        pout[r * dout + j] = acc;   // row-major scatter (spread full-chip)
    }
}

// K4: layers 3-4 + FC, one block per row (32 x 1024).
// Stage h3 row coalesced (7.2 KB), LDS gather chain with vectorized weight
// loads, shfl-reduce FC, direct out write.
__global__ __launch_bounds__(1024)
void tail34fc(const float* __restrict__ h3,
              const float* __restrict__ w3, const float* __restrict__ b3, const int* __restrict__ n3,
              const float* __restrict__ w4, const float* __restrict__ b4, const int* __restrict__ n4,
              const float* __restrict__ Wfc, const float* __restrict__ bfc,
              float* __restrict__ out)
{
    __shared__ float s3[D3];  // 7.2 KB
    __shared__ float s4[D4];  // 3.6 KB
    __shared__ float s5[D5];  // 1.8 KB
    __shared__ float red[2];

    const int r   = blockIdx.x;
    const int tid = threadIdx.x;

    // stage this row of h3 (coalesced float4, single iteration)
    if (tid < D3 / 4) {
        reinterpret_cast<float4*>(s3)[tid] =
            reinterpret_cast<const float4*>(h3 + (size_t)r * D3)[tid];
    }
    if (tid == 0) { red[0] = bfc[0]; red[1] = bfc[1]; }
    __syncthreads();

    // layer 3: 1800 -> 900 (single iteration, tid < 900)
    if (tid < D4) {
        const int*   kn = n3 + tid * KNB;
        const float* ww = w3 + tid * KNB;
        float acc = b3[tid];
#define S3_SRC(idx) s3[idx]
        GATHER25(acc, kn, ww, S3_SRC)
#undef S3_SRC
        s4[tid] = acc;
    }
    __syncthreads();

    // layer 4: 900 -> 450 (single iteration, tid < 450)
    if (tid < D5) {
        const int*   kn = n4 + tid * KNB;
        const float* ww = w4 + tid * KNB;
        float acc = b4[tid];
#define S4_SRC(idx) s4[idx]
        GATHER25(acc, kn, ww, S4_SRC)
#undef S4_SRC
        s5[tid] = acc;
    }
    __syncthreads();

    // FC: 450 -> 2
    float c0 = 0.0f, c1 = 0.0f;
    if (tid < D5) {
        const float v = s5[tid];
        c0 = v * Wfc[2 * tid + 0];
        c1 = v * Wfc[2 * tid + 1];
    }
#pragma unroll
    for (int off = 32; off > 0; off >>= 1) {
        c0 += __shfl_down(c0, off);
        c1 += __shfl_down(c1, off);
    }
    if ((tid & 63) == 0 && tid < D5) {
        atomicAdd(&red[0], c0);
        atomicAdd(&red[1], c1);
    }
    __syncthreads();
    if (tid < 2)
        out[2 * r + tid] = red[tid];
}

extern "C" void kernel_launch(void* const* d_in, const int* in_sizes, int n_in,
                              void* d_out, int out_size, void* d_ws, size_t ws_size,
                              hipStream_t stream)
{
    const float* x    = (const float*)d_in[0];
    const float* w0   = (const float*)d_in[1];
    const float* b0   = (const float*)d_in[2];
    const int*   knn0 = (const int*)  d_in[3];
    const float* w1   = (const float*)d_in[4];
    const float* b1   = (const float*)d_in[5];
    const int*   knn1 = (const int*)  d_in[6];
    const float* w2   = (const float*)d_in[7];
    const float* b2   = (const float*)d_in[8];
    const int*   knn2 = (const int*)  d_in[9];
    const float* w3   = (const float*)d_in[10];
    const float* b3   = (const float*)d_in[11];
    const int*   knn3 = (const int*)  d_in[12];
    const float* w4   = (const float*)d_in[13];
    const float* b4   = (const float*)d_in[14];
    const int*   knn4 = (const int*)  d_in[15];
    const float* Wfc  = (const float*)d_in[16];
    const float* bfc  = (const float*)d_in[17];
    float* out = (float*)d_out;

    // ws: h1t[D1][32] transposed | h2t[D2][32] transposed | h3[32][D3] row-major
    float* h1t = (float*)d_ws;
    float* h2t = h1t + (size_t)D1 * ROWS;
    float* h3  = h2t + (size_t)D2 * ROWS;

    // layer 0: x[:,T-1,:] -> h1t (transposed)
    l0_stage<<<dim3(D1 / 900, ROWS), dim3(256), 0, stream>>>(x, h1t, w0, b0, knn0);

    // layer 1: h1t -> h2t (full chip, 1800 pairs, transposed write)
    layer_t_k<<<dim3(450), dim3(256), 0, stream>>>(h1t, h2t, w1, b1, knn1, D2 / 2);

    // layer 2: h2t -> h3 (full chip, 900 pairs, ROW-major write)
    layer_t_k_rm<<<dim3(225), dim3(256), 0, stream>>>(h2t, h3, w2, b2, knn2, D3 / 2, D3);

    // layers 3-4 + FC: one block per row, direct write (no memset)
    tail34fc<<<dim3(ROWS), dim3(1024), 0, stream>>>(
        h3,
        w3, b3, knn3,
        w4, b4, knn4,
        Wfc, bfc, out);
}